// Round 1
// baseline (500.032 us; speedup 1.0000x reference)
//
#include <hip/hip_runtime.h>
#include <stdint.h>

// GIN conv: agg = segment_sum(val * x[col], row); h=(1+eps)x+agg;
// h=relu(h@W1+b1); h=relu(h@W2+b2); out=relu(h+bias).
// Strategy: build CSR per call (no float atomics), wave-per-node aggregate,
// bf16 MFMA GEMMs (threshold 0.255 is loose).

static constexpr int NN = 100000;
static constexpr int NE = 1600000;
static constexpr int DD = 128;

typedef float f32x4 __attribute__((ext_vector_type(4)));
typedef short s16x8 __attribute__((ext_vector_type(8)));

__device__ __forceinline__ uint16_t f2bf(float f) {
  uint32_t u = __float_as_uint(f);
  u += 0x7fffu + ((u >> 16) & 1u);   // round-to-nearest-even
  return (uint16_t)(u >> 16);
}

// ---------------- CSR build ----------------
__global__ __launch_bounds__(256) void k_zero(int* __restrict__ p, int n) {
  int i = blockIdx.x * 256 + threadIdx.x;
  if (i < n) p[i] = 0;
}

__global__ __launch_bounds__(256) void k_hist(const int* __restrict__ row,
                                              int* __restrict__ deg, int n) {
  int e = blockIdx.x * 256 + threadIdx.x;
  if (e < n) atomicAdd(&deg[row[e]], 1);
}

// block of 256 threads scans 1024 elements; writes block-local exclusive scan
__global__ __launch_bounds__(256) void k_scan_a(const int* __restrict__ deg,
                                                int* __restrict__ rowptr,
                                                int* __restrict__ bsum, int n) {
  __shared__ int lds[256];
  int tid = threadIdx.x;
  int base = blockIdx.x * 1024 + tid * 4;
  int v[4]; int tot = 0;
  #pragma unroll
  for (int j = 0; j < 4; ++j) {
    int i = base + j;
    v[j] = (i < n) ? deg[i] : 0;
    tot += v[j];
  }
  lds[tid] = tot; __syncthreads();
  for (int off = 1; off < 256; off <<= 1) {
    int t = (tid >= off) ? lds[tid - off] : 0;
    __syncthreads();
    lds[tid] += t;
    __syncthreads();
  }
  int s = lds[tid] - tot;  // exclusive
  #pragma unroll
  for (int j = 0; j < 4; ++j) {
    int i = base + j;
    if (i < n) rowptr[i] = s;
    s += v[j];
  }
  if (tid == 255) bsum[blockIdx.x] = lds[255];
}

__global__ __launch_bounds__(128) void k_scan_b(int* __restrict__ bsum, int nblk,
                                                int* __restrict__ rowptr_end) {
  __shared__ int lds[128];
  int tid = threadIdx.x;
  int v = (tid < nblk) ? bsum[tid] : 0;
  lds[tid] = v; __syncthreads();
  for (int off = 1; off < 128; off <<= 1) {
    int t = (tid >= off) ? lds[tid - off] : 0;
    __syncthreads();
    lds[tid] += t;
    __syncthreads();
  }
  if (tid < nblk) bsum[tid] = lds[tid] - v;  // exclusive
  if (tid == 127) *rowptr_end = lds[127];    // total == NE
}

__global__ __launch_bounds__(256) void k_scan_c(int* __restrict__ rowptr,
                                                int* __restrict__ cursor,
                                                const int* __restrict__ bsum, int n) {
  int tid = threadIdx.x;
  int base = blockIdx.x * 1024 + tid * 4;
  int add = bsum[blockIdx.x];
  #pragma unroll
  for (int j = 0; j < 4; ++j) {
    int i = base + j;
    if (i < n) {
      int r = rowptr[i] + add;
      rowptr[i] = r;
      cursor[i] = r;
    }
  }
}

__global__ __launch_bounds__(256) void k_scatter(const int* __restrict__ row,
                                                 const int* __restrict__ col,
                                                 const float* __restrict__ val,
                                                 int* __restrict__ cursor,
                                                 int2* __restrict__ es, int n) {
  int e = blockIdx.x * 256 + threadIdx.x;
  if (e < n) {
    int r = row[e];
    int pos = atomicAdd(&cursor[r], 1);
    int2 ev;
    ev.x = col[e];
    ev.y = __float_as_int(val[e]);
    es[pos] = ev;
  }
}

// ---------------- aggregate: one wave per node ----------------
// h[i] = (1+eps)*x[i] + sum_k val_k * x[col_k]; store as bf16 (GEMM input)
__global__ __launch_bounds__(256) void k_agg(const float* __restrict__ x,
                                             const int2* __restrict__ es,
                                             const int* __restrict__ rowptr,
                                             const float* __restrict__ eps,
                                             uint32_t* __restrict__ hb) {
  int wave = (blockIdx.x * 256 + threadIdx.x) >> 6;
  int lane = threadIdx.x & 63;
  if (wave >= NN) return;
  const float2* xr = (const float2*)x;  // 64 lanes x float2 = one 128-dim row
  float e = 1.0f + eps[0];
  float2 h = xr[wave * 64 + lane];
  h.x *= e; h.y *= e;
  int beg = rowptr[wave], end = rowptr[wave + 1];
  for (int k = beg; k < end; ++k) {
    int2 ev = es[k];
    float v = __int_as_float(ev.y);
    float2 xv = xr[ev.x * 64 + lane];
    h.x = fmaf(v, xv.x, h.x);
    h.y = fmaf(v, xv.y, h.y);
  }
  hb[wave * 64 + lane] = (uint32_t)f2bf(h.x) | ((uint32_t)f2bf(h.y) << 16);
}

// ---------------- bf16 MFMA GEMM: [nrows,128] @ [128,128] ----------------
// block = 4 waves = 64 rows; wave computes 16 rows x 128 cols.
// W (fp32, row-major [k][n]) staged transposed+bf16 in LDS so B-frags are
// contiguous 8-elem loads; +8 pad -> 2-way bank aliasing (free on CDNA4).
template <bool FINAL>
__global__ __launch_bounds__(256) void k_gemm(const uint16_t* __restrict__ A,
                                              const float* __restrict__ W,
                                              const float* __restrict__ bvec,
                                              const float* __restrict__ bias2,
                                              void* __restrict__ outp, int nrows) {
  __shared__ uint16_t wt[128 * 136];
  int tid = threadIdx.x;
  #pragma unroll 4
  for (int it = 0; it < 64; ++it) {
    int idx = tid + it * 256;
    int k = idx >> 7, n = idx & 127;
    wt[n * 136 + k] = f2bf(W[idx]);
  }
  __syncthreads();

  int wv = tid >> 6, l = tid & 63;
  int m16 = l & 15, qg = l >> 4;
  int i0 = blockIdx.x * 64 + wv * 16;
  int arow = i0 + m16;
  if (arow >= nrows) arow = nrows - 1;  // clamp: safe, stores are guarded

  f32x4 acc[8];
  #pragma unroll
  for (int t = 0; t < 8; ++t) acc[t] = f32x4{0.f, 0.f, 0.f, 0.f};

  #pragma unroll
  for (int k0 = 0; k0 < 128; k0 += 32) {
    // A-frag: lane holds A[m16][k0 + qg*8 .. +7] (8 contiguous bf16 = 16B)
    s16x8 a = *(const s16x8*)(A + (size_t)arow * 128 + k0 + qg * 8);
    #pragma unroll
    for (int n0 = 0; n0 < 8; ++n0) {
      // B-frag: lane holds B[k0+qg*8 .. +7][n0*16+m16] = wt[n][k..k+7]
      s16x8 b = *(const s16x8*)(&wt[(n0 * 16 + m16) * 136 + k0 + qg * 8]);
      acc[n0] = __builtin_amdgcn_mfma_f32_16x16x32_bf16(a, b, acc[n0], 0, 0, 0);
    }
  }

  // C/D layout: col = lane&15, row = (lane>>4)*4 + reg
  #pragma unroll
  for (int n0 = 0; n0 < 8; ++n0) {
    int col = n0 * 16 + m16;
    float bb = bvec[col];
    float b2 = FINAL ? bias2[col] : 0.0f;
    #pragma unroll
    for (int j = 0; j < 4; ++j) {
      int row = i0 + qg * 4 + j;
      if (row < nrows) {
        float v = acc[n0][j] + bb;
        v = fmaxf(v, 0.0f);
        if (FINAL) {
          v = fmaxf(v + b2, 0.0f);
          ((float*)outp)[(size_t)row * 128 + col] = v;
        } else {
          ((uint16_t*)outp)[(size_t)row * 128 + col] = f2bf(v);
        }
      }
    }
  }
}

extern "C" void kernel_launch(void* const* d_in, const int* in_sizes, int n_in,
                              void* d_out, int out_size, void* d_ws, size_t ws_size,
                              hipStream_t stream) {
  const float* x    = (const float*)d_in[0];
  const int*   erow = (const int*)d_in[1];
  const int*   ecol = (const int*)d_in[2];
  const float* eval = (const float*)d_in[3];
  const float* W1   = (const float*)d_in[4];
  const float* b1   = (const float*)d_in[5];
  const float* W2   = (const float*)d_in[6];
  const float* b2   = (const float*)d_in[7];
  const float* eps  = (const float*)d_in[8];
  const float* bias = (const float*)d_in[9];

  char* w = (char*)d_ws;
  size_t off = 0;
  auto take = [&](size_t bytes) -> void* {
    void* p = w + off;
    off = (off + bytes + 255) & ~(size_t)255;
    return p;
  };
  uint32_t* hb     = (uint32_t*)take((size_t)NN * DD * 2);  // bf16 h, packed x2
  uint16_t* h2b    = (uint16_t*)take((size_t)NN * DD * 2);  // bf16 layer-1 out
  int2*     es     = (int2*)take((size_t)NE * 8);           // CSR (col, val)
  int*      deg    = (int*)take((size_t)NN * 4);
  int*      rowptr = (int*)take((size_t)(NN + 1) * 4);
  int*      cursor = (int*)take((size_t)NN * 4);
  int*      bsum   = (int*)take(512);

  int nblk = (NN + 1023) / 1024;  // 98 (<=128 for scan_b)

  k_zero<<<(NN + 255) / 256, 256, 0, stream>>>(deg, NN);
  k_hist<<<(NE + 255) / 256, 256, 0, stream>>>(erow, deg, NE);
  k_scan_a<<<nblk, 256, 0, stream>>>(deg, rowptr, bsum, NN);
  k_scan_b<<<1, 128, 0, stream>>>(bsum, nblk, rowptr + NN);
  k_scan_c<<<nblk, 256, 0, stream>>>(rowptr, cursor, bsum, NN);
  k_scatter<<<(NE + 255) / 256, 256, 0, stream>>>(erow, ecol, eval, cursor, es, NE);
  k_agg<<<(NN + 3) / 4, 256, 0, stream>>>(x, es, rowptr, eps, hb);
  k_gemm<false><<<(NN + 63) / 64, 256, 0, stream>>>((const uint16_t*)hb, W1, b1,
                                                    nullptr, h2b, NN);
  k_gemm<true><<<(NN + 63) / 64, 256, 0, stream>>>(h2b, W2, b2, bias, d_out, NN);
}

// Round 2
// 420.374 us; speedup vs baseline: 1.1895x; 1.1895x over previous
//
#include <hip/hip_runtime.h>
#include <stdint.h>

// GIN conv: agg = segment_sum(val * x[col], row); h=(1+eps)x+agg;
// h=relu(h@W1+b1); h=relu(h@W2+b2); out=relu(h+bias).
// R1: bf16 x-gather + MLP-8 edge chunks in k_agg; 256-row GEMM blocks.

static constexpr int NN = 100000;
static constexpr int NE = 1600000;
static constexpr int DD = 128;

typedef float f32x4 __attribute__((ext_vector_type(4)));
typedef short s16x8 __attribute__((ext_vector_type(8)));

__device__ __forceinline__ uint16_t f2bf(float f) {
  uint32_t u = __float_as_uint(f);
  u += 0x7fffu + ((u >> 16) & 1u);   // round-to-nearest-even
  return (uint16_t)(u >> 16);
}
__device__ __forceinline__ float2 bf2f(uint32_t w) {
  float2 r;
  r.x = __uint_as_float(w << 16);
  r.y = __uint_as_float(w & 0xffff0000u);
  return r;
}

// ---------------- prep: x (fp32) -> packed bf16 pairs ----------------
__global__ __launch_bounds__(256) void k_cvt(const float* __restrict__ x,
                                             uint32_t* __restrict__ xb, int nw) {
  int i = blockIdx.x * 256 + threadIdx.x;
  if (i < nw) {
    float2 v = ((const float2*)x)[i];
    xb[i] = (uint32_t)f2bf(v.x) | ((uint32_t)f2bf(v.y) << 16);
  }
}

// ---------------- CSR build ----------------
__global__ __launch_bounds__(256) void k_zero(int* __restrict__ p, int n,
                                              int2* __restrict__ es_pad) {
  int i = blockIdx.x * 256 + threadIdx.x;
  if (i < n) p[i] = 0;
  if (blockIdx.x == 0 && threadIdx.x < 8) es_pad[threadIdx.x] = int2{0, 0};
}

__global__ __launch_bounds__(256) void k_hist(const int* __restrict__ row,
                                              int* __restrict__ deg, int n) {
  int e = blockIdx.x * 256 + threadIdx.x;
  if (e < n) atomicAdd(&deg[row[e]], 1);
}

__global__ __launch_bounds__(256) void k_scan_a(const int* __restrict__ deg,
                                                int* __restrict__ rowptr,
                                                int* __restrict__ bsum, int n) {
  __shared__ int lds[256];
  int tid = threadIdx.x;
  int base = blockIdx.x * 1024 + tid * 4;
  int v[4]; int tot = 0;
  #pragma unroll
  for (int j = 0; j < 4; ++j) {
    int i = base + j;
    v[j] = (i < n) ? deg[i] : 0;
    tot += v[j];
  }
  lds[tid] = tot; __syncthreads();
  for (int off = 1; off < 256; off <<= 1) {
    int t = (tid >= off) ? lds[tid - off] : 0;
    __syncthreads();
    lds[tid] += t;
    __syncthreads();
  }
  int s = lds[tid] - tot;  // exclusive
  #pragma unroll
  for (int j = 0; j < 4; ++j) {
    int i = base + j;
    if (i < n) rowptr[i] = s;
    s += v[j];
  }
  if (tid == 255) bsum[blockIdx.x] = lds[255];
}

__global__ __launch_bounds__(128) void k_scan_b(int* __restrict__ bsum, int nblk,
                                                int* __restrict__ rowptr_end) {
  __shared__ int lds[128];
  int tid = threadIdx.x;
  int v = (tid < nblk) ? bsum[tid] : 0;
  lds[tid] = v; __syncthreads();
  for (int off = 1; off < 128; off <<= 1) {
    int t = (tid >= off) ? lds[tid - off] : 0;
    __syncthreads();
    lds[tid] += t;
    __syncthreads();
  }
  if (tid < nblk) bsum[tid] = lds[tid] - v;  // exclusive
  if (tid == 127) *rowptr_end = lds[127];    // total == NE
}

__global__ __launch_bounds__(256) void k_scan_c(int* __restrict__ rowptr,
                                                int* __restrict__ cursor,
                                                const int* __restrict__ bsum, int n) {
  int tid = threadIdx.x;
  int base = blockIdx.x * 1024 + tid * 4;
  int add = bsum[blockIdx.x];
  #pragma unroll
  for (int j = 0; j < 4; ++j) {
    int i = base + j;
    if (i < n) {
      int r = rowptr[i] + add;
      rowptr[i] = r;
      cursor[i] = r;
    }
  }
}

__global__ __launch_bounds__(256) void k_scatter(const int* __restrict__ row,
                                                 const int* __restrict__ col,
                                                 const float* __restrict__ val,
                                                 int* __restrict__ cursor,
                                                 int2* __restrict__ es, int n) {
  int e = blockIdx.x * 256 + threadIdx.x;
  if (e < n) {
    int r = row[e];
    int pos = atomicAdd(&cursor[r], 1);
    int2 ev;
    ev.x = col[e];
    ev.y = __float_as_int(val[e]);
    es[pos] = ev;
  }
}

// ---------------- aggregate: one wave per node, MLP-8 chunks ----------------
// h[i] = (1+eps)*x[i] + sum_k val_k * x[col_k]; x gathered as bf16; out bf16.
__global__ __launch_bounds__(256) void k_agg(const uint32_t* __restrict__ xb,
                                             const int2* __restrict__ es,
                                             const int* __restrict__ rowptr,
                                             const float* __restrict__ eps,
                                             uint32_t* __restrict__ hb) {
  int wave = (blockIdx.x * 256 + threadIdx.x) >> 6;
  int lane = threadIdx.x & 63;
  if (wave >= NN) return;
  float e = 1.0f + eps[0];
  float2 h = bf2f(xb[(size_t)wave * 64 + lane]);
  h.x *= e; h.y *= e;
  int beg = rowptr[wave], end = rowptr[wave + 1];
  for (int k = beg; k < end; k += 8) {
    int2 ev[8];
    #pragma unroll
    for (int j = 0; j < 8; ++j) ev[j] = es[k + j];  // es padded by 8 zero entries
    uint32_t xw[8];
    #pragma unroll
    for (int j = 0; j < 8; ++j) xw[j] = xb[(size_t)ev[j].x * 64 + lane];
    #pragma unroll
    for (int j = 0; j < 8; ++j) {
      float v = (k + j < end) ? __int_as_float(ev[j].y) : 0.0f;
      float2 xv = bf2f(xw[j]);
      h.x = fmaf(v, xv.x, h.x);
      h.y = fmaf(v, xv.y, h.y);
    }
  }
  hb[(size_t)wave * 64 + lane] = (uint32_t)f2bf(h.x) | ((uint32_t)f2bf(h.y) << 16);
}

// ---------------- bf16 MFMA GEMM: [nrows,128] @ [128,128] ----------------
// block = 4 waves = 256 rows; wave computes 64 rows (4 m-tiles) x 128 cols.
// W (fp32 [k][n]) staged transposed+bf16 in LDS (+8 pad -> 2-way, free).
// B-fragments reused across the 4 m-tiles.
template <bool FINAL>
__global__ __launch_bounds__(256, 2) void k_gemm(const uint16_t* __restrict__ A,
                                                 const float* __restrict__ W,
                                                 const float* __restrict__ bvec,
                                                 const float* __restrict__ bias2,
                                                 void* __restrict__ outp, int nrows) {
  __shared__ uint16_t wt[128 * 136];
  int tid = threadIdx.x;
  #pragma unroll 4
  for (int it = 0; it < 64; ++it) {
    int idx = tid + it * 256;
    int k = idx >> 7, n = idx & 127;
    wt[n * 136 + k] = f2bf(W[idx]);
  }
  __syncthreads();

  int wv = tid >> 6, l = tid & 63;
  int m16 = l & 15, qg = l >> 4;
  int w0 = blockIdx.x * 256 + wv * 64;  // wave's first row

  int arow[4];
  #pragma unroll
  for (int mt = 0; mt < 4; ++mt) {
    int r = w0 + mt * 16 + m16;
    arow[mt] = (r < nrows) ? r : (nrows - 1);  // clamp; stores are guarded
  }

  f32x4 acc[4][8];
  #pragma unroll
  for (int mt = 0; mt < 4; ++mt)
    #pragma unroll
    for (int t = 0; t < 8; ++t) acc[mt][t] = f32x4{0.f, 0.f, 0.f, 0.f};

  #pragma unroll
  for (int k0 = 0; k0 < 128; k0 += 32) {
    s16x8 a[4];
    #pragma unroll
    for (int mt = 0; mt < 4; ++mt)
      a[mt] = *(const s16x8*)(A + (size_t)arow[mt] * 128 + k0 + qg * 8);
    #pragma unroll
    for (int n0 = 0; n0 < 8; ++n0) {
      s16x8 b = *(const s16x8*)(&wt[(n0 * 16 + m16) * 136 + k0 + qg * 8]);
      #pragma unroll
      for (int mt = 0; mt < 4; ++mt)
        acc[mt][n0] = __builtin_amdgcn_mfma_f32_16x16x32_bf16(a[mt], b, acc[mt][n0], 0, 0, 0);
    }
  }

  // C/D layout: col = lane&15, row = (lane>>4)*4 + reg
  #pragma unroll
  for (int mt = 0; mt < 4; ++mt) {
    #pragma unroll
    for (int n0 = 0; n0 < 8; ++n0) {
      int col = n0 * 16 + m16;
      float bb = bvec[col];
      float b2 = FINAL ? bias2[col] : 0.0f;
      #pragma unroll
      for (int j = 0; j < 4; ++j) {
        int row = w0 + mt * 16 + qg * 4 + j;
        if (row < nrows) {
          float v = acc[mt][n0][j] + bb;
          v = fmaxf(v, 0.0f);
          if (FINAL) {
            v = fmaxf(v + b2, 0.0f);
            ((float*)outp)[(size_t)row * 128 + col] = v;
          } else {
            ((uint16_t*)outp)[(size_t)row * 128 + col] = f2bf(v);
          }
        }
      }
    }
  }
}

extern "C" void kernel_launch(void* const* d_in, const int* in_sizes, int n_in,
                              void* d_out, int out_size, void* d_ws, size_t ws_size,
                              hipStream_t stream) {
  const float* x    = (const float*)d_in[0];
  const int*   erow = (const int*)d_in[1];
  const int*   ecol = (const int*)d_in[2];
  const float* eval = (const float*)d_in[3];
  const float* W1   = (const float*)d_in[4];
  const float* b1   = (const float*)d_in[5];
  const float* W2   = (const float*)d_in[6];
  const float* b2   = (const float*)d_in[7];
  const float* eps  = (const float*)d_in[8];
  const float* bias = (const float*)d_in[9];

  char* w = (char*)d_ws;
  size_t off = 0;
  auto take = [&](size_t bytes) -> void* {
    void* p = w + off;
    off = (off + bytes + 255) & ~(size_t)255;
    return p;
  };
  uint32_t* xb     = (uint32_t*)take((size_t)NN * 64 * 4);  // bf16 x, packed x2
  uint32_t* hb     = (uint32_t*)take((size_t)NN * 64 * 4);  // bf16 h, packed x2
  uint16_t* h2b    = (uint16_t*)take((size_t)NN * DD * 2);  // bf16 layer-1 out
  int2*     es     = (int2*)take((size_t)(NE + 8) * 8);     // CSR (col,val)+pad
  int*      deg    = (int*)take((size_t)NN * 4);
  int*      rowptr = (int*)take((size_t)(NN + 1) * 4);
  int*      cursor = (int*)take((size_t)NN * 4);
  int*      bsum   = (int*)take(512);

  int nblk = (NN + 1023) / 1024;  // 98 (<=128 for scan_b)

  k_cvt<<<(NN * 64 + 255) / 256, 256, 0, stream>>>(x, xb, NN * 64);
  k_zero<<<(NN + 255) / 256, 256, 0, stream>>>(deg, NN, es + NE);
  k_hist<<<(NE + 255) / 256, 256, 0, stream>>>(erow, deg, NE);
  k_scan_a<<<nblk, 256, 0, stream>>>(deg, rowptr, bsum, NN);
  k_scan_b<<<1, 128, 0, stream>>>(bsum, nblk, rowptr + NN);
  k_scan_c<<<nblk, 256, 0, stream>>>(rowptr, cursor, bsum, NN);
  k_scatter<<<(NE + 255) / 256, 256, 0, stream>>>(erow, ecol, eval, cursor, es, NE);
  k_agg<<<(NN + 3) / 4, 256, 0, stream>>>(xb, es, rowptr, eps, hb);
  k_gemm<false><<<(NN + 255) / 256, 256, 0, stream>>>((const uint16_t*)hb, W1, b1,
                                                      nullptr, h2b, NN);
  k_gemm<true><<<(NN + 255) / 256, 256, 0, stream>>>(h2b, W2, b2, bias, d_out, NN);
}

// Round 3
// 270.530 us; speedup vs baseline: 1.8483x; 1.5539x over previous
//
#include <hip/hip_runtime.h>
#include <stdint.h>

// GIN conv: agg = segment_sum(val * x[col], row); h=(1+eps)x+agg;
// h=relu(h@W1+b1); h=relu(h@W2+b2); out=relu(h+bias).
// R2: CSR build via two-level bucket sort (no global hist, no cross-XCD
// write amplification). k_agg: bf16 gather + MLP-8. GEMMs: bf16 MFMA.

static constexpr int NN = 100000;
static constexpr int NE = 1600000;
static constexpr int DD = 128;
static constexpr int NB = 196;    // buckets of 512 rows (100000/512 -> 196)
static constexpr int EPB = 4096;  // edges per partition block
static constexpr int PB = (NE + EPB - 1) / EPB;  // 391

typedef float f32x4 __attribute__((ext_vector_type(4)));
typedef short s16x8 __attribute__((ext_vector_type(8)));

__device__ __forceinline__ uint16_t f2bf(float f) {
  uint32_t u = __float_as_uint(f);
  u += 0x7fffu + ((u >> 16) & 1u);   // round-to-nearest-even
  return (uint16_t)(u >> 16);
}
__device__ __forceinline__ float2 bf2f(uint32_t w) {
  float2 r;
  r.x = __uint_as_float(w << 16);
  r.y = __uint_as_float(w & 0xffff0000u);
  return r;
}

// inclusive Hillis-Steele scan over first WIDTH entries of s0/s1.
// ALL threads of the block must call (barriers inside). Result in returned ptr.
template <int WIDTH>
__device__ __forceinline__ int* scan_inc(int* s0, int* s1, int tid) {
  int* pin = s0;
  int* pout = s1;
  for (int off = 1; off < WIDTH; off <<= 1) {
    if (tid < WIDTH) pout[tid] = pin[tid] + ((tid >= off) ? pin[tid - off] : 0);
    __syncthreads();
    int* tmp = pin; pin = pout; pout = tmp;
  }
  return pin;
}

// ---------------- prep: x (fp32) -> packed bf16 pairs ----------------
__global__ __launch_bounds__(256) void k_cvt(const float* __restrict__ x,
                                             uint32_t* __restrict__ xb, int nw) {
  int i = blockIdx.x * 256 + threadIdx.x;
  if (i < nw) {
    float2 v = ((const float2*)x)[i];
    xb[i] = (uint32_t)f2bf(v.x) | ((uint32_t)f2bf(v.y) << 16);
  }
}

__global__ __launch_bounds__(256) void k_init(int* __restrict__ bucket_tot,
                                              int2* __restrict__ es_pad) {
  int t = threadIdx.x;
  if (t < NB) bucket_tot[t] = 0;
  if (t < 8) es_pad[t] = int2{0, 0};
}

// ---------------- phase 1: partition edges into 196 buckets ----------------
// Each block sorts its 4096 edges by bucket into an LDS stage, then writes its
// own contiguous 32KB chunk (full-line coalesced). Entry: {col | rib<<17, val}.
__global__ __launch_bounds__(1024) void k_part(const int* __restrict__ erow,
                                               const int* __restrict__ ecol,
                                               const float* __restrict__ eval,
                                               int2* __restrict__ part,
                                               int* __restrict__ runstart,
                                               int* __restrict__ bucket_tot) {
  __shared__ int hist[NB];
  __shared__ int cur[NB];
  __shared__ int s0[256], s1[256];
  __shared__ int2 stage[EPB];
  int t = threadIdx.x;
  int base = blockIdx.x * EPB;
  int cnt = min(EPB, NE - base);

  if (t < NB) hist[t] = 0;
  __syncthreads();

  int pb[4], pk[4], pv[4];
  #pragma unroll
  for (int j = 0; j < 4; ++j) {
    int i = t + j * 1024;
    pb[j] = -1;
    if (i < cnt) {
      int e = base + i;
      int r = erow[e];
      int b = r >> 9;
      pb[j] = b;
      pk[j] = ecol[e] | ((r & 511) << 17);
      pv[j] = __float_as_int(eval[e]);
      atomicAdd(&hist[b], 1);
    }
  }
  __syncthreads();

  if (t < 256) s0[t] = (t < NB) ? hist[t] : 0;
  __syncthreads();
  int* inc = scan_inc<256>(s0, s1, t);

  if (t < NB) {
    int h = hist[t];
    int st = inc[t] - h;  // exclusive
    cur[t] = st;
    runstart[blockIdx.x * (NB + 1) + t] = st;
    atomicAdd(&bucket_tot[t], h);
  }
  if (t == 0) runstart[blockIdx.x * (NB + 1) + NB] = cnt;
  __syncthreads();

  #pragma unroll
  for (int j = 0; j < 4; ++j) {
    if (pb[j] >= 0) {
      int off = atomicAdd(&cur[pb[j]], 1);
      stage[off] = int2{pk[j], pv[j]};
    }
  }
  __syncthreads();

  for (int i = t; i < cnt; i += 1024) part[base + i] = stage[i];
}

// ---------------- bucket bases: exclusive scan of 196 totals ----------------
__global__ __launch_bounds__(256) void k_bbase(const int* __restrict__ tot,
                                               int* __restrict__ bbase) {
  __shared__ int s0[256], s1[256];
  int t = threadIdx.x;
  int v = (t < NB) ? tot[t] : 0;
  s0[t] = v;
  __syncthreads();
  int* inc = scan_inc<256>(s0, s1, t);
  if (t < NB) bbase[t] = inc[t] - v;
  if (t == NB - 1) bbase[NB] = inc[t];
}

// ---------------- phase 2: per-bucket CSR (one block per bucket) ----------------
// Gathers the bucket's 391 runs, LDS-hist over 512 rows-in-bucket, writes
// rowptr + ticket-scatters es within the bucket's own 64KB region.
__global__ __launch_bounds__(1024) void k_bucket(const int2* __restrict__ part,
                                                 const int* __restrict__ runstart,
                                                 const int* __restrict__ bbase,
                                                 int2* __restrict__ es,
                                                 int* __restrict__ rowptr) {
  __shared__ int cum[PB + 1];
  __shared__ int rbas[PB];
  __shared__ int hist[512];
  __shared__ int rps[512];
  __shared__ int cur[512];
  __shared__ int s0[512], s1[512];
  int b = blockIdx.x, t = threadIdx.x;

  int len = 0;
  if (t < PB) {
    int rs = runstart[t * (NB + 1) + b];
    int re = runstart[t * (NB + 1) + b + 1];
    len = re - rs;
    rbas[t] = t * EPB + rs;
  }
  if (t < 512) s0[t] = (t < PB) ? len : 0;
  __syncthreads();
  int* inc1 = scan_inc<512>(s0, s1, t);
  if (t < PB) cum[t] = inc1[t] - len;
  if (t == 0) cum[PB] = inc1[PB - 1];
  if (t < 512) hist[t] = 0;
  __syncthreads();

  int total = cum[PB];
  int base_out = bbase[b];

  // pass 1: gather edges (binary search run), histogram rows-in-bucket
  int pk[16], pv[16];
  #pragma unroll
  for (int j = 0; j < 16; ++j) {
    int s = t + j * 1024;
    pk[j] = -1;
    if (s < total) {
      int lo = 0, hi = PB;  // invariant: cum[lo] <= s < cum[hi]
      while (hi - lo > 1) {
        int mid = (lo + hi) >> 1;
        if (cum[mid] <= s) lo = mid; else hi = mid;
      }
      int2 ev = part[rbas[lo] + (s - cum[lo])];
      pk[j] = ev.x; pv[j] = ev.y;
      atomicAdd(&hist[ev.x >> 17], 1);
    }
  }
  __syncthreads();

  if (t < 512) s0[t] = hist[t];
  __syncthreads();
  int* inc2 = scan_inc<512>(s0, s1, t);
  if (t < 512) {
    int ex = inc2[t] - hist[t];
    rps[t] = ex;
    cur[t] = ex;
  }
  __syncthreads();

  if (t < 512) {
    int row = b * 512 + t;
    if (row <= NN) rowptr[row] = base_out + rps[t];
  }

  // pass 2: ticket-scatter into this bucket's contiguous es region
  #pragma unroll
  for (int j = 0; j < 16; ++j) {
    if (pk[j] >= 0) {
      int rib = pk[j] >> 17;
      int off = atomicAdd(&cur[rib], 1);
      es[base_out + off] = int2{pk[j] & 0x1FFFF, pv[j]};
    }
  }
}

// ---------------- aggregate: one wave per node, MLP-8 chunks ----------------
__global__ __launch_bounds__(256) void k_agg(const uint32_t* __restrict__ xb,
                                             const int2* __restrict__ es,
                                             const int* __restrict__ rowptr,
                                             const float* __restrict__ eps,
                                             uint32_t* __restrict__ hb) {
  int wave = (blockIdx.x * 256 + threadIdx.x) >> 6;
  int lane = threadIdx.x & 63;
  if (wave >= NN) return;
  float e = 1.0f + eps[0];
  float2 h = bf2f(xb[(size_t)wave * 64 + lane]);
  h.x *= e; h.y *= e;
  int beg = rowptr[wave], end = rowptr[wave + 1];
  for (int k = beg; k < end; k += 8) {
    int2 ev[8];
    #pragma unroll
    for (int j = 0; j < 8; ++j) ev[j] = es[k + j];  // es padded by 8 zero entries
    uint32_t xw[8];
    #pragma unroll
    for (int j = 0; j < 8; ++j) xw[j] = xb[(size_t)ev[j].x * 64 + lane];
    #pragma unroll
    for (int j = 0; j < 8; ++j) {
      float v = (k + j < end) ? __int_as_float(ev[j].y) : 0.0f;
      float2 xv = bf2f(xw[j]);
      h.x = fmaf(v, xv.x, h.x);
      h.y = fmaf(v, xv.y, h.y);
    }
  }
  hb[(size_t)wave * 64 + lane] = (uint32_t)f2bf(h.x) | ((uint32_t)f2bf(h.y) << 16);
}

// ---------------- bf16 MFMA GEMM: [nrows,128] @ [128,128] ----------------
template <bool FINAL>
__global__ __launch_bounds__(256, 2) void k_gemm(const uint16_t* __restrict__ A,
                                                 const float* __restrict__ W,
                                                 const float* __restrict__ bvec,
                                                 const float* __restrict__ bias2,
                                                 void* __restrict__ outp, int nrows) {
  __shared__ uint16_t wt[128 * 136];
  int tid = threadIdx.x;
  #pragma unroll 4
  for (int it = 0; it < 64; ++it) {
    int idx = tid + it * 256;
    int k = idx >> 7, n = idx & 127;
    wt[n * 136 + k] = f2bf(W[idx]);
  }
  __syncthreads();

  int wv = tid >> 6, l = tid & 63;
  int m16 = l & 15, qg = l >> 4;
  int w0 = blockIdx.x * 256 + wv * 64;

  int arow[4];
  #pragma unroll
  for (int mt = 0; mt < 4; ++mt) {
    int r = w0 + mt * 16 + m16;
    arow[mt] = (r < nrows) ? r : (nrows - 1);  // clamp; stores guarded
  }

  f32x4 acc[4][8];
  #pragma unroll
  for (int mt = 0; mt < 4; ++mt)
    #pragma unroll
    for (int n0 = 0; n0 < 8; ++n0) acc[mt][n0] = f32x4{0.f, 0.f, 0.f, 0.f};

  #pragma unroll
  for (int k0 = 0; k0 < 128; k0 += 32) {
    s16x8 a[4];
    #pragma unroll
    for (int mt = 0; mt < 4; ++mt)
      a[mt] = *(const s16x8*)(A + (size_t)arow[mt] * 128 + k0 + qg * 8);
    #pragma unroll
    for (int n0 = 0; n0 < 8; ++n0) {
      s16x8 bfr = *(const s16x8*)(&wt[(n0 * 16 + m16) * 136 + k0 + qg * 8]);
      #pragma unroll
      for (int mt = 0; mt < 4; ++mt)
        acc[mt][n0] = __builtin_amdgcn_mfma_f32_16x16x32_bf16(a[mt], bfr, acc[mt][n0], 0, 0, 0);
    }
  }

  // C/D layout: col = lane&15, row = (lane>>4)*4 + reg
  #pragma unroll
  for (int mt = 0; mt < 4; ++mt) {
    #pragma unroll
    for (int n0 = 0; n0 < 8; ++n0) {
      int col = n0 * 16 + m16;
      float bb = bvec[col];
      float b2 = FINAL ? bias2[col] : 0.0f;
      #pragma unroll
      for (int j = 0; j < 4; ++j) {
        int row = w0 + mt * 16 + qg * 4 + j;
        if (row < nrows) {
          float v = acc[mt][n0][j] + bb;
          v = fmaxf(v, 0.0f);
          if (FINAL) {
            v = fmaxf(v + b2, 0.0f);
            ((float*)outp)[(size_t)row * 128 + col] = v;
          } else {
            ((uint16_t*)outp)[(size_t)row * 128 + col] = f2bf(v);
          }
        }
      }
    }
  }
}

extern "C" void kernel_launch(void* const* d_in, const int* in_sizes, int n_in,
                              void* d_out, int out_size, void* d_ws, size_t ws_size,
                              hipStream_t stream) {
  const float* x    = (const float*)d_in[0];
  const int*   erow = (const int*)d_in[1];
  const int*   ecol = (const int*)d_in[2];
  const float* eval = (const float*)d_in[3];
  const float* W1   = (const float*)d_in[4];
  const float* b1   = (const float*)d_in[5];
  const float* W2   = (const float*)d_in[6];
  const float* b2   = (const float*)d_in[7];
  const float* eps  = (const float*)d_in[8];
  const float* bias = (const float*)d_in[9];

  char* w = (char*)d_ws;
  size_t off = 0;
  auto take = [&](size_t bytes) -> void* {
    void* p = w + off;
    off = (off + bytes + 255) & ~(size_t)255;
    return p;
  };
  uint32_t* xb     = (uint32_t*)take((size_t)NN * 64 * 4);   // bf16 x, packed
  uint32_t* hb     = (uint32_t*)take((size_t)NN * 64 * 4);   // bf16 h, packed
  uint16_t* h2b    = (uint16_t*)take((size_t)NN * DD * 2);   // layer-1 out; ALIASES part
  int2*     part   = (int2*)h2b;   // 12.8MB <= 25.6MB; disjoint lifetime vs h2b
  int2*     es     = (int2*)take((size_t)(NE + 8) * 8);      // CSR (col,val)+pad
  int*      rowptr = (int*)take((size_t)(NN + 1) * 4);
  int*      runst  = (int*)take((size_t)PB * (NB + 1) * 4);  // run starts
  int*      btot   = (int*)take((size_t)(NB + 1) * 4);
  int*      bbase  = (int*)take((size_t)(NB + 1) * 4);
  (void)ws_size;

  k_cvt<<<(NN * 64 + 255) / 256, 256, 0, stream>>>(x, xb, NN * 64);
  k_init<<<1, 256, 0, stream>>>(btot, es + NE);
  k_part<<<PB, 1024, 0, stream>>>(erow, ecol, eval, part, runst, btot);
  k_bbase<<<1, 256, 0, stream>>>(btot, bbase);
  k_bucket<<<NB, 1024, 0, stream>>>(part, runst, bbase, es, rowptr);
  k_agg<<<(NN + 3) / 4, 256, 0, stream>>>(xb, es, rowptr, eps, hb);
  k_gemm<false><<<(NN + 255) / 256, 256, 0, stream>>>((const uint16_t*)hb, W1, b1,
                                                      nullptr, h2b, NN);
  k_gemm<true><<<(NN + 255) / 256, 256, 0, stream>>>(h2b, W2, b2, bias, d_out, NN);
}

// Round 4
// 262.671 us; speedup vs baseline: 1.9036x; 1.0299x over previous
//
#include <hip/hip_runtime.h>
#include <stdint.h>

// GIN conv: agg = segment_sum(val * x[col], row); h=(1+eps)x+agg;
// h=relu(h@W1+b1); h=relu(h@W2+b2); out=relu(h+bias).
// R3: scalar edge stream in k_agg (s_load edges, saddr gathers);
// fused 2-layer MFMA MLP; merged init/bbase; 5 kernels total.

static constexpr int NN = 100000;
static constexpr int NE = 1600000;
static constexpr int NB = 196;    // buckets of 512 rows
static constexpr int EPB = 4096;  // edges per partition block
static constexpr int PB = (NE + EPB - 1) / EPB;  // 391

typedef float f32x4 __attribute__((ext_vector_type(4)));
typedef short s16x8 __attribute__((ext_vector_type(8)));

__device__ __forceinline__ uint16_t f2bf(float f) {
  uint32_t u = __float_as_uint(f);
  u += 0x7fffu + ((u >> 16) & 1u);   // round-to-nearest-even
  return (uint16_t)(u >> 16);
}
__device__ __forceinline__ float2 bf2f(uint32_t w) {
  float2 r;
  r.x = __uint_as_float(w << 16);
  r.y = __uint_as_float(w & 0xffff0000u);
  return r;
}

// inclusive Hillis-Steele scan over first WIDTH entries of s0/s1.
// ALL threads of the block must call (barriers inside).
template <int WIDTH>
__device__ __forceinline__ int* scan_inc(int* s0, int* s1, int tid) {
  int* pin = s0;
  int* pout = s1;
  for (int off = 1; off < WIDTH; off <<= 1) {
    if (tid < WIDTH) pout[tid] = pin[tid] + ((tid >= off) ? pin[tid - off] : 0);
    __syncthreads();
    int* tmp = pin; pin = pout; pout = tmp;
  }
  return pin;
}

// ---------------- prep: x -> packed bf16 pairs; + zero-init btot/es pad ----
__global__ __launch_bounds__(256) void k_cvt(const float* __restrict__ x,
                                             uint32_t* __restrict__ xb, int nq,
                                             int* __restrict__ btot,
                                             int2* __restrict__ es_pad) {
  int i = blockIdx.x * 256 + threadIdx.x;
  if (i < nq) {
    float4 v = ((const float4*)x)[i];
    uint2 o;
    o.x = (uint32_t)f2bf(v.x) | ((uint32_t)f2bf(v.y) << 16);
    o.y = (uint32_t)f2bf(v.z) | ((uint32_t)f2bf(v.w) << 16);
    ((uint2*)xb)[i] = o;
  }
  if (blockIdx.x == 0) {
    int t = threadIdx.x;
    if (t < NB) btot[t] = 0;
    if (t < 8) es_pad[t] = int2{0, 0};
  }
}

// ---------------- phase 1: partition edges into 196 buckets ----------------
__global__ __launch_bounds__(1024) void k_part(const int* __restrict__ erow,
                                               const int* __restrict__ ecol,
                                               const float* __restrict__ eval,
                                               int2* __restrict__ part,
                                               int* __restrict__ runstart,
                                               int* __restrict__ bucket_tot) {
  __shared__ int hist[NB];
  __shared__ int cur[NB];
  __shared__ int s0[256], s1[256];
  __shared__ int2 stage[EPB];
  int t = threadIdx.x;
  int base = blockIdx.x * EPB;
  int cnt = min(EPB, NE - base);

  if (t < NB) hist[t] = 0;
  __syncthreads();

  int pb[4], pk[4], pv[4];
  #pragma unroll
  for (int j = 0; j < 4; ++j) {
    int i = t + j * 1024;
    pb[j] = -1;
    if (i < cnt) {
      int e = base + i;
      int r = erow[e];
      int b = r >> 9;
      pb[j] = b;
      pk[j] = ecol[e] | ((r & 511) << 17);
      pv[j] = __float_as_int(eval[e]);
      atomicAdd(&hist[b], 1);
    }
  }
  __syncthreads();

  if (t < 256) s0[t] = (t < NB) ? hist[t] : 0;
  __syncthreads();
  int* inc = scan_inc<256>(s0, s1, t);

  if (t < NB) {
    int h = hist[t];
    int st = inc[t] - h;  // exclusive
    cur[t] = st;
    runstart[blockIdx.x * (NB + 1) + t] = st;
    atomicAdd(&bucket_tot[t], h);
  }
  if (t == 0) runstart[blockIdx.x * (NB + 1) + NB] = cnt;
  __syncthreads();

  #pragma unroll
  for (int j = 0; j < 4; ++j) {
    if (pb[j] >= 0) {
      int off = atomicAdd(&cur[pb[j]], 1);
      stage[off] = int2{pk[j], pv[j]};
    }
  }
  __syncthreads();

  for (int i = t; i < cnt; i += 1024) part[base + i] = stage[i];
}

// ---------------- phase 2: per-bucket CSR (one block per bucket) -----------
__global__ __launch_bounds__(1024) void k_bucket(const int2* __restrict__ part,
                                                 const int* __restrict__ runstart,
                                                 const int* __restrict__ btot,
                                                 int2* __restrict__ es,
                                                 int* __restrict__ rowptr) {
  __shared__ int cum[PB + 1];
  __shared__ int rbas[PB];
  __shared__ int hist[512];
  __shared__ int rps[512];
  __shared__ int cur[512];
  __shared__ int s0[512], s1[512];
  __shared__ int sbase;
  int b = blockIdx.x, t = threadIdx.x;

  // inline bucket-base: exclusive scan of btot up to b
  int bt = (t < NB) ? btot[t] : 0;
  if (t < 512) s0[t] = (t < 256) ? ((t < NB) ? bt : 0) : 0;
  __syncthreads();
  {
    int* incb = scan_inc<256>(s0, s1, t);
    if (t == b) sbase = incb[b] - bt;
  }
  __syncthreads();
  int base_out = sbase;

  int len = 0;
  if (t < PB) {
    int rs = runstart[t * (NB + 1) + b];
    int re = runstart[t * (NB + 1) + b + 1];
    len = re - rs;
    rbas[t] = t * EPB + rs;
  }
  __syncthreads();
  if (t < 512) s0[t] = (t < PB) ? len : 0;
  __syncthreads();
  int* inc1 = scan_inc<512>(s0, s1, t);
  if (t < PB) cum[t] = inc1[t] - len;
  if (t == 0) cum[PB] = inc1[PB - 1];
  if (t < 512) hist[t] = 0;
  __syncthreads();

  int total = cum[PB];

  // pass 1: gather edges (binary search run), histogram rows-in-bucket
  int pk[16], pv[16];
  #pragma unroll
  for (int j = 0; j < 16; ++j) {
    int s = t + j * 1024;
    pk[j] = -1;
    if (s < total) {
      int lo = 0, hi = PB;  // invariant: cum[lo] <= s < cum[hi]
      while (hi - lo > 1) {
        int mid = (lo + hi) >> 1;
        if (cum[mid] <= s) lo = mid; else hi = mid;
      }
      int2 ev = part[rbas[lo] + (s - cum[lo])];
      pk[j] = ev.x; pv[j] = ev.y;
      atomicAdd(&hist[ev.x >> 17], 1);
    }
  }
  __syncthreads();

  if (t < 512) s0[t] = hist[t];
  __syncthreads();
  int* inc2 = scan_inc<512>(s0, s1, t);
  if (t < 512) {
    int ex = inc2[t] - hist[t];
    rps[t] = ex;
    cur[t] = ex;
  }
  __syncthreads();

  if (t < 512) {
    int row = b * 512 + t;
    if (row <= NN) rowptr[row] = base_out + rps[t];
  }

  // pass 2: ticket-scatter into this bucket's contiguous es region
  #pragma unroll
  for (int j = 0; j < 16; ++j) {
    if (pk[j] >= 0) {
      int rib = pk[j] >> 17;
      int off = atomicAdd(&cur[rib], 1);
      es[base_out + off] = int2{pk[j] & 0x1FFFF, pv[j]};
    }
  }
}

// ---------------- aggregate: one wave per node, scalar edge stream ---------
// Edge records are wave-uniform -> readfirstlane forces them into SGPRs:
// s_load edge stream, saddr-form gathers (scalar base + lane*4), scalar mask.
__global__ __launch_bounds__(256) void k_agg(const uint32_t* __restrict__ xb,
                                             const int2* __restrict__ es,
                                             const int* __restrict__ rowptr,
                                             const float* __restrict__ eps,
                                             uint32_t* __restrict__ hb) {
  int wid = (blockIdx.x * 256 + threadIdx.x) >> 6;
  int wave = __builtin_amdgcn_readfirstlane(wid);
  int lane = threadIdx.x & 63;
  float e = 1.0f + eps[0];
  float2 h = bf2f(xb[(size_t)wave * 64 + lane]);
  h.x *= e; h.y *= e;
  int beg = __builtin_amdgcn_readfirstlane(rowptr[wave]);
  int end = __builtin_amdgcn_readfirstlane(rowptr[wave + 1]);
  for (int k = beg; k < end; k += 8) {
    int scol[8]; float sval[8];
    #pragma unroll
    for (int j = 0; j < 8; ++j) {
      int2 ev = es[k + j];  // es padded by 8 zero entries at the very end
      scol[j] = __builtin_amdgcn_readfirstlane(ev.x);
      int vb = __builtin_amdgcn_readfirstlane(ev.y);
      sval[j] = (k + j < end) ? __int_as_float(vb) : 0.0f;
    }
    uint32_t xw[8];
    #pragma unroll
    for (int j = 0; j < 8; ++j)
      xw[j] = xb[((size_t)scol[j] << 6) + lane];
    #pragma unroll
    for (int j = 0; j < 8; ++j) {
      float2 xv = bf2f(xw[j]);
      h.x = fmaf(sval[j], xv.x, h.x);
      h.y = fmaf(sval[j], xv.y, h.y);
    }
  }
  hb[(size_t)wave * 64 + lane] = (uint32_t)f2bf(h.x) | ((uint32_t)f2bf(h.y) << 16);
}

// ---------------- fused 2-layer MFMA MLP: [64,128] rows per block ----------
// out = relu(relu(relu(h@W1+b1)@W2+b2)+bias). W staged transposed bf16 in LDS
// (restaged for layer 2); interlayer h1 kept in LDS bf16. 3 blocks/CU.
__global__ __launch_bounds__(256, 3) void k_mlp(const uint16_t* __restrict__ A,
                                                const float* __restrict__ W1,
                                                const float* __restrict__ b1,
                                                const float* __restrict__ W2,
                                                const float* __restrict__ b2,
                                                const float* __restrict__ bias,
                                                float* __restrict__ out, int nrows) {
  __shared__ uint16_t wt[128 * 136];
  __shared__ uint16_t h1[64 * 136];
  int tid = threadIdx.x;

  #pragma unroll 4
  for (int it = 0; it < 64; ++it) {
    int idx = tid + it * 256;
    wt[(idx & 127) * 136 + (idx >> 7)] = f2bf(W1[idx]);
  }
  __syncthreads();

  int wv = tid >> 6, l = tid & 63;
  int m16 = l & 15, qg = l >> 4;
  int r0 = blockIdx.x * 64 + wv * 16;  // wave's 16-row tile
  int arow = r0 + m16;
  if (arow >= nrows) arow = nrows - 1;  // clamp; stores guarded

  f32x4 acc[8];
  #pragma unroll
  for (int n0 = 0; n0 < 8; ++n0) acc[n0] = f32x4{0.f, 0.f, 0.f, 0.f};

  #pragma unroll
  for (int k0 = 0; k0 < 128; k0 += 32) {
    s16x8 a = *(const s16x8*)(A + (size_t)arow * 128 + k0 + qg * 8);
    #pragma unroll
    for (int n0 = 0; n0 < 8; ++n0) {
      s16x8 bfr = *(const s16x8*)(&wt[(n0 * 16 + m16) * 136 + k0 + qg * 8]);
      acc[n0] = __builtin_amdgcn_mfma_f32_16x16x32_bf16(a, bfr, acc[n0], 0, 0, 0);
    }
  }

  // epilogue 1: relu(acc + b1) -> h1 LDS (bf16). C/D: col=lane&15, row=qg*4+j
  #pragma unroll
  for (int n0 = 0; n0 < 8; ++n0) {
    int col = n0 * 16 + m16;
    float bb = b1[col];
    #pragma unroll
    for (int j = 0; j < 4; ++j) {
      int lr = wv * 16 + qg * 4 + j;
      h1[lr * 136 + col] = f2bf(fmaxf(acc[n0][j] + bb, 0.0f));
    }
  }
  __syncthreads();

  #pragma unroll 4
  for (int it = 0; it < 64; ++it) {
    int idx = tid + it * 256;
    wt[(idx & 127) * 136 + (idx >> 7)] = f2bf(W2[idx]);
  }
  #pragma unroll
  for (int n0 = 0; n0 < 8; ++n0) acc[n0] = f32x4{0.f, 0.f, 0.f, 0.f};
  __syncthreads();

  #pragma unroll
  for (int k0 = 0; k0 < 128; k0 += 32) {
    s16x8 a = *(const s16x8*)(&h1[(wv * 16 + m16) * 136 + k0 + qg * 8]);
    #pragma unroll
    for (int n0 = 0; n0 < 8; ++n0) {
      s16x8 bfr = *(const s16x8*)(&wt[(n0 * 16 + m16) * 136 + k0 + qg * 8]);
      acc[n0] = __builtin_amdgcn_mfma_f32_16x16x32_bf16(a, bfr, acc[n0], 0, 0, 0);
    }
  }

  // epilogue 2: relu(relu(acc + b2) + bias) -> out (fp32)
  #pragma unroll
  for (int n0 = 0; n0 < 8; ++n0) {
    int col = n0 * 16 + m16;
    float bb = b2[col];
    float b3 = bias[col];
    #pragma unroll
    for (int j = 0; j < 4; ++j) {
      int row = r0 + qg * 4 + j;
      if (row < nrows) {
        float v = fmaxf(fmaxf(acc[n0][j] + bb, 0.0f) + b3, 0.0f);
        out[(size_t)row * 128 + col] = v;
      }
    }
  }
}

extern "C" void kernel_launch(void* const* d_in, const int* in_sizes, int n_in,
                              void* d_out, int out_size, void* d_ws, size_t ws_size,
                              hipStream_t stream) {
  const float* x    = (const float*)d_in[0];
  const int*   erow = (const int*)d_in[1];
  const int*   ecol = (const int*)d_in[2];
  const float* eval = (const float*)d_in[3];
  const float* W1   = (const float*)d_in[4];
  const float* b1   = (const float*)d_in[5];
  const float* W2   = (const float*)d_in[6];
  const float* b2   = (const float*)d_in[7];
  const float* eps  = (const float*)d_in[8];
  const float* bias = (const float*)d_in[9];

  char* w = (char*)d_ws;
  size_t off = 0;
  auto take = [&](size_t bytes) -> void* {
    void* p = w + off;
    off = (off + bytes + 255) & ~(size_t)255;
    return p;
  };
  uint32_t* xb     = (uint32_t*)take((size_t)NN * 64 * 4);   // bf16 x, packed
  uint32_t* hb     = (uint32_t*)take((size_t)NN * 64 * 4);   // bf16 h, packed
  int2*     part   = (int2*)take((size_t)NE * 8);
  int2*     es     = (int2*)take((size_t)(NE + 8) * 8);      // CSR (col,val)+pad
  int*      rowptr = (int*)take((size_t)(NN + 1) * 4);
  int*      runst  = (int*)take((size_t)PB * (NB + 1) * 4);
  int*      btot   = (int*)take((size_t)(NB + 1) * 4);
  (void)ws_size;

  k_cvt<<<(NN * 32 + 255) / 256, 256, 0, stream>>>(x, xb, NN * 32, btot, es + NE);
  k_part<<<PB, 1024, 0, stream>>>(erow, ecol, eval, part, runst, btot);
  k_bucket<<<NB, 1024, 0, stream>>>(part, runst, btot, es, rowptr);
  k_agg<<<(NN + 3) / 4, 256, 0, stream>>>(xb, es, rowptr, eps, hb);
  k_mlp<<<(NN + 63) / 64, 256, 0, stream>>>((const uint16_t*)hb, W1, b1, W2, b2,
                                            bias, (float*)d_out, NN);
}